// Round 9
// baseline (535.188 us; speedup 1.0000x reference)
//
#include <hip/hip_runtime.h>

#define HH 512
#define WW 512
#define CH 3
#define NTX 64           // one column per lane -> lane-stride-1 LDS (proven conflict-free)
#define NTY 4            // 256-thread blocks (proven better than 128 in R7)
#define PY  2            // vertical pixel pair per thread
#define SPANY (NTY * PY)         // 8 rows per block
#define TILE_W 70                // 64 + 6 halo
#define TILE_H (SPANY + 6)       // 14
#define CSTR (TILE_H * TILE_W)   // 980 floats

// exp(-50*d^2 - r2/4.5) == exp2(K1*d^2 + K2*r2)
#define K1f (-72.13475204444817f)   // -50 * log2(e)
#define K2f (-0.3205988979753252f)  // -(1/4.5) * log2(e)

__device__ __forceinline__ int reflect_idx(int v, int n) {
    v = (v < 0) ? -v : v;
    return (v >= n) ? (2 * (n - 1) - v) : v;
}

__device__ __forceinline__ float fast_exp2(float x) {
#if __has_builtin(__builtin_amdgcn_exp2f)
    return __builtin_amdgcn_exp2f(x);
#else
    return exp2f(x);
#endif
}

// cap VGPR (~85) so the unrolled body cannot hoist-explode like R5 (204 VGPR)
__global__ __launch_bounds__(NTX * NTY, 6)
void bilateral_kernel(const float* __restrict__ in, float* __restrict__ out) {
    __shared__ float sm[CH * CSTR];   // 11760 B

    const int bx0 = blockIdx.x * NTX;
    const int by0 = blockIdx.y * SPANY;
    const int b   = blockIdx.z;
    const int lx  = threadIdx.x;
    const float* inb = in + (size_t)b * CH * HH * WW;

    // ---- cooperative halo staging (lane-stride-1 b32: conflict-free, proven) ----
    for (int c = 0; c < CH; ++c) {
        for (int ty = threadIdx.y; ty < TILE_H; ty += NTY) {
            const int gy = reflect_idx(by0 + ty - 3, HH);
            const float* grow = inb + (c * HH + gy) * WW;
            float* srow = &sm[c * CSTR + ty * TILE_W];
            const int gx0 = reflect_idx(bx0 + lx - 3, WW);
            srow[lx] = grow[gx0];
            if (lx < TILE_W - NTX) {
                const int gx1 = reflect_idx(bx0 + lx + NTX - 3, WW);
                srow[lx + NTX] = grow[gx1];
            }
        }
    }
    __syncthreads();

    const int rb = threadIdx.y * PY;            // first pixel row (tile coords)
    const float* smb = sm + rb * TILE_W + lx;   // single per-lane base, imm offsets below

    // centers: pixel py0 at tile row rb+3, py1 at rb+4 (col lx+3)
    const float c0x = smb[0 * CSTR + 3 * TILE_W + 3];
    const float c1x = smb[1 * CSTR + 3 * TILE_W + 3];
    const float c2x = smb[2 * CSTR + 3 * TILE_W + 3];
    const float c0y = smb[0 * CSTR + 4 * TILE_W + 3];
    const float c1y = smb[1 * CSTR + 4 * TILE_W + 3];
    const float c2y = smb[2 * CSTR + 4 * TILE_W + 3];

    // center tap has w == 1 exactly -> pre-accumulate and skip it in the loop
    float n0x = c0x, n1x = c1x, n2x = c2x, denx = 1.0f;
    float n0y = c0y, n1y = c1y, n2y = c2y, deny = 1.0f;

    // rows touched: py0 window = r 0..6 (i=r), py1 window = r 1..7 (i=r-1)
#pragma unroll
    for (int r = 0; r < 8; ++r) {
        float A0[7], A1[7], A2[7];
#pragma unroll
        for (int j = 0; j < 7; ++j) {
            A0[j] = smb[0 * CSTR + r * TILE_W + j];
            A1[j] = smb[1 * CSTR + r * TILE_W + j];
            A2[j] = smb[2 * CSTR + r * TILE_W + j];
        }
#pragma unroll
        for (int j = 0; j < 7; ++j) {
            const float v0 = A0[j], v1 = A1[j], v2 = A2[j];
            if (r <= 6 && !(r == 3 && j == 3)) {               // pixel py0, kernel row i=r
                const float d  = fabsf(v0 - c0x) + fabsf(v1 - c1x) + fabsf(v2 - c2x);
                const float lk = (float)((r - 3) * (r - 3) + (j - 3) * (j - 3)) * K2f;
                const float w  = fast_exp2(fmaf(d * K1f, d, lk));
                n0x = fmaf(w, v0, n0x); n1x = fmaf(w, v1, n1x); n2x = fmaf(w, v2, n2x);
                denx += w;
            }
            if (r >= 1 && !(r == 4 && j == 3)) {               // pixel py1, kernel row i=r-1
                const int  i  = r - 1;
                const float d  = fabsf(v0 - c0y) + fabsf(v1 - c1y) + fabsf(v2 - c2y);
                const float lk = (float)((i - 3) * (i - 3) + (j - 3) * (j - 3)) * K2f;
                const float w  = fast_exp2(fmaf(d * K1f, d, lk));
                n0y = fmaf(w, v0, n0y); n1y = fmaf(w, v1, n1y); n2y = fmaf(w, v2, n2y);
                deny += w;
            }
        }
    }

    float* outb = out + (size_t)b * CH * HH * WW;
    const int x  = bx0 + lx;
    const int y0 = by0 + rb;
    const float invx = 1.0f / denx;   // den >= 1
    const float invy = 1.0f / deny;
    outb[(0 * HH + y0) * WW + x] = n0x * invx;
    outb[(1 * HH + y0) * WW + x] = n1x * invx;
    outb[(2 * HH + y0) * WW + x] = n2x * invx;
    outb[(0 * HH + y0 + 1) * WW + x] = n0y * invy;
    outb[(1 * HH + y0 + 1) * WW + x] = n1y * invy;
    outb[(2 * HH + y0 + 1) * WW + x] = n2y * invy;
}

extern "C" void kernel_launch(void* const* d_in, const int* in_sizes, int n_in,
                              void* d_out, int out_size, void* d_ws, size_t ws_size,
                              hipStream_t stream) {
    const float* in = (const float*)d_in[0];
    float* out = (float*)d_out;
    const int B = in_sizes[0] / (CH * HH * WW);
    dim3 grid(WW / NTX, HH / SPANY, B);
    dim3 block(NTX, NTY, 1);
    bilateral_kernel<<<grid, block, 0, stream>>>(in, out);
}